// Round 5
// baseline (115162.488 us; speedup 1.0000x reference)
//
#include <hip/hip_runtime.h>
#include <stdint.h>

#define U_ 1536
#define D_ 768
#define N_ 4096
#define UNF 6
#define LOG2E 1.4426950408889634f
#define NBLK 128
#define CPB 12           // columns per scan block
#define TPB 768          // threads per scan block
#define SG 8             // steps per sensory block
#define TOTAL_TAGS (N_*UNF)

typedef unsigned int uint4v __attribute__((ext_vector_type(4)));
typedef unsigned int uint2v __attribute__((ext_vector_type(2)));

// ---------- helpers ----------
__device__ __forceinline__ uint32_t f2bf(float f) {
    uint32_t u = __float_as_uint(f);
    u += 0x7FFFu + ((u >> 16) & 1u);   // RNE to bf16
    return u >> 16;
}
__device__ __forceinline__ uint32_t pack2(float hi, float lo) {
    return (f2bf(hi) << 16) | f2bf(lo);
}

// ---------- K0: pack weights (bf16, PAIR layout), rt, clear board ----------
// pair p: jg = p/768, k2 = (p%768)>>6, lane = p&63 -> rows i0=lane+128*k2, i1=i0+64
// pk_rec[2p] = entry(i0,jg), pk_rec[2p+1] = entry(i1,jg)
__global__ void k_pack(const float* __restrict__ sigma, const float* __restrict__ mu,
                       const float* __restrict__ w, const float* __restrict__ erev,
                       const float* __restrict__ ssig, const float* __restrict__ smu,
                       const float* __restrict__ sw, const float* __restrict__ serev,
                       const float* __restrict__ dt,
                       uint2* __restrict__ pk_rec, uint2* __restrict__ pk_sens,
                       float* __restrict__ rt, unsigned long long* __restrict__ vpub)
{
    int gsz = gridDim.x * blockDim.x;
    int g0  = blockIdx.x * blockDim.x + threadIdx.x;
    for (int p = g0; p < U_*U_/2; p += gsz) {
        int jg   = p / 768;
        int rmd  = p - jg*768;
        int k2   = rmd >> 6, lane = rmd & 63;
        int i0   = lane + (k2 << 7);
        int i1   = i0 + 64;
        int inA  = i0*U_ + jg;
        int inB  = i1*U_ + jg;
        float sgA = sigma[inA] * LOG2E, sgB = sigma[inB] * LOG2E;
        uint2 a, bq;
        a.x  = pack2(sgA, sgA*mu[inA]);  a.y  = pack2(w[inA], w[inA]*erev[inA]);
        bq.x = pack2(sgB, sgB*mu[inB]);  bq.y = pack2(w[inB], w[inB]*erev[inB]);
        pk_rec[2*p]   = a;
        pk_rec[2*p+1] = bq;
    }
    // sensory pack, orientation [d][j]
    for (int o = g0; o < D_*U_; o += gsz) {
        float sg = ssig[o] * LOG2E;
        uint2 p; p.x = pack2(sg, sg*smu[o]); p.y = pack2(sw[o], sw[o]*serev[o]);
        pk_sens[o] = p;
    }
    for (int o = g0; o < N_; o += gsz) rt[o] = 6.0f / fmaxf(dt[o], 0.001f);
    for (int o = g0; o < 2*U_; o += gsz) vpub[o] = 0ull;   // clear board (graph replay)
}

// ---------- K1: sensory sums for all steps ----------
__global__ __launch_bounds__(256) void k_sens(const float* __restrict__ x,
        const float* __restrict__ iw, const float* __restrict__ ib,
        const uint2* __restrict__ pk_sens, float2* __restrict__ sens)
{
    __shared__ float xs[SG][D_];
    int ct = blockIdx.x % 6;
    int g  = blockIdx.x / 6;
    int n0 = g * SG;
    for (int idx = threadIdx.x; idx < SG*D_; idx += 256) {
        int s = idx / D_, d = idx - s*D_;
        xs[s][d] = x[(size_t)(n0+s)*D_ + d] * iw[d] + ib[d];
    }
    __syncthreads();
    int j = ct*256 + threadIdx.x;
    float an[SG], bn[SG];
#pragma unroll
    for (int s = 0; s < SG; ++s) { an[s] = 0.0f; bn[s] = 0.0f; }
    for (int d = 0; d < D_; ++d) {
        uint2 m = pk_sens[d*U_ + j];
        float s2 = __uint_as_float(m.x & 0xFFFF0000u);
        float p2 = __uint_as_float(m.x << 16);
        float wv = __uint_as_float(m.y & 0xFFFF0000u);
        float wev= __uint_as_float(m.y << 16);
#pragma unroll
        for (int s = 0; s < SG; ++s) {
            float e  = __builtin_amdgcn_exp2f(fmaf(-s2, xs[s][d], p2));
            float sg = __builtin_amdgcn_rcpf(1.0f + e);
            an[s] = fmaf(wev, sg, an[s]);
            bn[s] = fmaf(wv,  sg, bn[s]);
        }
    }
#pragma unroll
    for (int s = 0; s < SG; ++s)
        sens[(size_t)(n0+s)*U_ + j] = make_float2(an[s], bn[s]);
}

// ---------- K2: persistent scan, per-wave publish, 1 barrier/round ----------
__global__ __launch_bounds__(TPB, 1) void k_scan(
        const uint2* __restrict__ pk_rec, const float2* __restrict__ sens,
        const float* __restrict__ rt, unsigned long long* __restrict__ vpub,
        const float* __restrict__ gleak, const float* __restrict__ vleak,
        const float* __restrict__ cm, float* __restrict__ out)
{
    __shared__ alignas(16) uint2 pk_s[CPB*U_];   // 147456 B, pair layout
    __shared__ float  v_s[2][U_];                // 12288 B double buffer
    __shared__ float2 sens_s[2][CPB];
    __shared__ float  rt_s[2];

    const int tid = threadIdx.x;
    const int b   = blockIdx.x;

    for (int o = tid; o < CPB*U_; o += TPB) pk_s[o] = pk_rec[(size_t)b*CPB*U_ + o];
    for (int o = tid; o < U_;     o += TPB) { v_s[0][o] = 0.0f; v_s[1][o] = 0.0f; }

    const int col  = tid >> 6;    // 0..11, wave col owns column b*12+col
    const int lane = tid & 63;
    const int jgo  = b*CPB + col;

    // per-wave publisher constants (lane 0 only meaningful)
    float glk = 0.0f, gvl = 0.0f, cmv = 0.0f, prev = 0.0f;
    if (lane == 0) {
        glk = gleak[jgo]; gvl = glk * vleak[jgo]; cmv = cm[jgo];
    }
    if (tid >= 64 && tid < 64+CPB) sens_s[0][tid-64] = sens[(size_t)b*CPB + (tid-64)];
    if (tid == 76) rt_s[0] = rt[0];

    // poll mapping: 762 pollers, one 16B chunk (2 tagged granules) each; own 6 skipped
    const bool isPoll = (tid < 6*NBLK - 6);
    int c = 0;
    if (isPoll) c = tid + (tid >= 6*b ? 6 : 0);

    __syncthreads();

    int tag = 1;
    for (int n = 0; n < N_; ++n) {
        float2 pf_sens = make_float2(0.0f, 0.0f);
        float  pf_rt = 0.0f;
        if (n + 1 < N_) {
            if (tid >= 64 && tid < 64+CPB) pf_sens = sens[(size_t)(n+1)*U_ + b*CPB + (tid-64)];
            if (tid == 76) pf_rt = rt[n+1];
        }
        for (int u = 0; u < UNF; ++u, ++tag) {
            const int rp = tag & 1;       // write parity (this round's values)
            const int rd = rp ^ 1;        // read parity (previous values)
            const bool last = (tag == TOTAL_TAGS);

            // ---- pre-issue poll load: latency overlaps gate compute ----
            uint4v pkt;
            uint64_t paddr = 0;
            if (!last && isPoll) {
                paddr = (uint64_t)vpub + ((size_t)rp*U_)*8 + (size_t)c*16;
                asm volatile("global_load_dwordx4 %0, %1, off sc1"
                             : "=v"(pkt) : "v"(paddr) : "memory");
            }

            // ---- gates: 12 x (b128 pair + 2 v reads + 2 gates) ----
            float num0 = 0.0f, num1 = 0.0f, den0 = 0.0f, den1 = 0.0f;
            const uint4v* pp = (const uint4v*)pk_s + (size_t)col*768;
            const float* vb = &v_s[rd][lane];
#pragma unroll
            for (int k2 = 0; k2 < 12; ++k2) {
                uint4v q = pp[(k2 << 6) + lane];
                float va = vb[k2*128];
                float vc = vb[k2*128 + 64];
                float sA = __uint_as_float(q.x & 0xFFFF0000u);
                float pA = __uint_as_float(q.x << 16);
                float wA = __uint_as_float(q.y & 0xFFFF0000u);
                float eA = __uint_as_float(q.y << 16);
                float gA = __builtin_amdgcn_rcpf(1.0f + __builtin_amdgcn_exp2f(fmaf(-sA, va, pA)));
                num0 = fmaf(eA, gA, num0); den0 = fmaf(wA, gA, den0);
                float sB = __uint_as_float(q.z & 0xFFFF0000u);
                float pB = __uint_as_float(q.z << 16);
                float wB = __uint_as_float(q.w & 0xFFFF0000u);
                float eB = __uint_as_float(q.w << 16);
                float gB = __builtin_amdgcn_rcpf(1.0f + __builtin_amdgcn_exp2f(fmaf(-sB, vc, pB)));
                num1 = fmaf(eB, gB, num1); den1 = fmaf(wB, gB, den1);
            }
            float num = num0 + num1, den = den0 + den1;
#pragma unroll
            for (int mk = 32; mk >= 1; mk >>= 1) {
                num += __shfl_xor(num, mk, 64);
                den += __shfl_xor(den, mk, 64);
            }

            // ---- per-wave publish (lane 0), no inter-wave barrier needed ----
            if (lane == 0) {
                float rtv = rt_s[n & 1];
                float2 sv = sens_s[n & 1][col];
                float cmt = cmv * rtv;
                float nm = cmt * prev + gvl + num + sv.x;
                float dn = cmt + glk + den + sv.y + 1e-8f;
                float vn = nm / dn;
                prev = vn;
                v_s[rp][jgo] = vn;                     // own value direct to LDS
                if (last) {
                    out[jgo] = vn;
                } else {
                    uint2v pk; pk.x = __float_as_uint(vn); pk.y = (unsigned)tag;
                    uint64_t saddr = (uint64_t)vpub + ((size_t)rp*U_ + jgo)*8;
                    asm volatile("global_store_dwordx2 %0, %1, off sc1"
                                 :: "v"(saddr), "v"(pk) : "memory");
                }
            }

            if (!last) {
                if (isPoll) {
                    unsigned t32 = (unsigned)tag;
                    // check pre-issued load; vmcnt(0) also orders publisher's store
                    asm volatile("s_waitcnt vmcnt(0)" ::: "memory");
                    int guard = 0;
                    while (!(pkt.y == t32 && pkt.w == t32)) {
                        if (++guard > (1 << 21)) break;   // visible fail, no hang
                        if (guard > 2) __builtin_amdgcn_s_sleep(1);
                        asm volatile("global_load_dwordx4 %0, %1, off sc1\n\t"
                                     "s_waitcnt vmcnt(0)"
                                     : "=v"(pkt) : "v"(paddr) : "memory");
                    }
                    float2 vv;
                    vv.x = __uint_as_float(pkt.x);
                    vv.y = __uint_as_float(pkt.z);
                    *(float2*)&v_s[rp][2*c] = vv;
                }
                if (u == UNF-1) {
                    if (tid >= 64 && tid < 64+CPB) sens_s[(n+1) & 1][tid-64] = pf_sens;
                    if (tid == 76) rt_s[(n+1) & 1] = pf_rt;
                }
                __syncthreads();   // single barrier per unfold
            }
        }
    }
}

// ---------- launch ----------
extern "C" void kernel_launch(void* const* d_in, const int* in_sizes, int n_in,
                              void* d_out, int out_size, void* d_ws, size_t ws_size,
                              hipStream_t stream)
{
    (void)in_sizes; (void)n_in; (void)out_size;
    const float* x     = (const float*)d_in[0];
    const float* dt    = (const float*)d_in[1];
    const float* iw    = (const float*)d_in[2];
    const float* ib    = (const float*)d_in[3];
    const float* gleak = (const float*)d_in[4];
    const float* vleak = (const float*)d_in[5];
    const float* cm    = (const float*)d_in[6];
    const float* sigma = (const float*)d_in[7];
    const float* mu    = (const float*)d_in[8];
    const float* w     = (const float*)d_in[9];
    const float* erev  = (const float*)d_in[10];
    const float* ssig  = (const float*)d_in[11];
    const float* smu   = (const float*)d_in[12];
    const float* sw    = (const float*)d_in[13];
    const float* serev = (const float*)d_in[14];

    size_t need = (size_t)N_*U_*8 + (size_t)U_*U_*8 + (size_t)D_*U_*8 + (size_t)N_*4
                + (size_t)2*U_*8;
    if (ws_size < need) return;   // insufficient scratch -> fail visibly

    char* ws = (char*)d_ws;
    float2* sens   = (float2*)ws;                 ws += (size_t)N_*U_*8;
    uint2*  pk_rec = (uint2*)ws;                  ws += (size_t)U_*U_*8;
    uint2*  pk_sns = (uint2*)ws;                  ws += (size_t)D_*U_*8;
    float*  rt     = (float*)ws;                  ws += (size_t)N_*4;
    unsigned long long* vpub = (unsigned long long*)ws;

    k_pack<<<2048, 256, 0, stream>>>(sigma, mu, w, erev, ssig, smu, sw, serev, dt,
                                     pk_rec, pk_sns, rt, vpub);
    k_sens<<<(N_/SG)*6, 256, 0, stream>>>(x, iw, ib, pk_sns, sens);
    // 128 blocks x ~156 KiB static LDS -> 1 block/CU, 128 < 256 CUs,
    // all blocks structurally co-resident (spin-exchange safe).
    k_scan<<<NBLK, TPB, 0, stream>>>(pk_rec, sens, rt, vpub,
                                     gleak, vleak, cm, (float*)d_out);
}